// Round 1
// baseline (1044.835 us; speedup 1.0000x reference)
//
#include <hip/hip_runtime.h>

#define NTOT 8192
#define DDIM 256
#define BM 16
#define BN 256
#define NEG_BIG -9e15f

// ---------------- Kernel 1: per-row scores s1 = h@a[:D], s2 = h@a[D:] -------
__global__ __launch_bounds__(256) void gat_scores(const float* __restrict__ h,
                                                  const float* __restrict__ a,
                                                  float* __restrict__ s1,
                                                  float* __restrict__ s2) {
  int row  = blockIdx.x * 4 + (threadIdx.x >> 6);  // one wave per row
  int lane = threadIdx.x & 63;
  const float* hr = h + (size_t)row * DDIM;
  float p1 = 0.f, p2 = 0.f;
#pragma unroll
  for (int k = 0; k < DDIM / 64; ++k) {
    int idx  = lane + 64 * k;
    float hv = hr[idx];
    p1 += hv * a[idx];
    p2 += hv * a[DDIM + idx];
  }
#pragma unroll
  for (int off = 32; off > 0; off >>= 1) {
    p1 += __shfl_down(p1, off, 64);
    p2 += __shfl_down(p2, off, 64);
  }
  if (lane == 0) { s1[row] = p1; s2[row] = p2; }
}

// ---------------- Kernel 2: fused masked softmax + P@h (flash-style) --------
// Block: 256 threads (4 waves), owns BM=16 output rows.
// Loop over j in BN=256 tiles: logits -> online softmax -> fp32 accumulate.
__global__ __launch_bounds__(256) void gat_attn(const float* __restrict__ h,
                                                const int*   __restrict__ adj,
                                                const float* __restrict__ s1g,
                                                const float* __restrict__ s2g,
                                                float* __restrict__ out) {
  __shared__ float p_tile[BM][BN + 1];   // +1 pad: breaks phase-A write conflicts
  __shared__ float s2t[BN];
  __shared__ float red[BM][16];
  __shared__ float m_sh[BM], l_sh[BM], alpha_sh[BM], s1_sh[BM];

  const int t  = threadIdx.x;
  const int r0 = blockIdx.x * BM;

  // phase-A roles: 16 threads per row (row group is wave-contained)
  const int rA = t >> 4;   // 0..15
  const int cA = t & 15;   // 0..15
  // accumulate roles: wave w handles rows {w, w+4, w+8, w+12}, lane owns 4 cols
  const int cg = t & 63;   // float4 column group (d0 = 4*cg)
  const int w  = t >> 6;   // wave id 0..3

  if (t < BM) {
    m_sh[t]  = NEG_BIG;
    l_sh[t]  = 0.f;
    s1_sh[t] = s1g[r0 + t];
  }
  float4 acc0 = make_float4(0.f, 0.f, 0.f, 0.f);
  float4 acc1 = make_float4(0.f, 0.f, 0.f, 0.f);
  float4 acc2 = make_float4(0.f, 0.f, 0.f, 0.f);
  float4 acc3 = make_float4(0.f, 0.f, 0.f, 0.f);
  __syncthreads();

  const int* adj_row = adj + (size_t)(r0 + rA) * NTOT;

  for (int j0 = 0; j0 < NTOT; j0 += BN) {
    // ---- stage s2 tile ----
    s2t[t] = s2g[j0 + t];
    __syncthreads();

    // ---- masked leaky-relu logits + tile max (16 threads per row) ----
    const float s1v = s1_sh[rA];
    float lmax = NEG_BIG;
#pragma unroll
    for (int k = 0; k < BN / 16; ++k) {
      int   jj = cA + 16 * k;
      int   av = adj_row[j0 + jj];
      float e  = s1v + s2t[jj];
      e = (e > 0.f) ? e : 0.01f * e;      // leaky_relu(0.01)
      e = (av > 0) ? e : NEG_BIG;         // mask (matches jnp.where semantics)
      p_tile[rA][jj] = e;
      lmax = fmaxf(lmax, e);
    }
    red[rA][cA] = lmax;                    // row group is within one wave: lockstep-safe
    float tm = red[rA][0];
#pragma unroll
    for (int k = 1; k < 16; ++k) tm = fmaxf(tm, red[rA][k]);
    const float m_old = m_sh[rA];
    const float m_new = fmaxf(m_old, tm);

    // ---- p = exp(e - m_new), tile sum ----
    float lsum = 0.f;
#pragma unroll
    for (int k = 0; k < BN / 16; ++k) {
      int   jj = cA + 16 * k;
      float p  = __expf(p_tile[rA][jj] - m_new);  // NEG_BIG - m_new -> exp underflows to 0
      p_tile[rA][jj] = p;
      lsum += p;
    }
    red[rA][cA] = lsum;                    // same-wave: no barrier needed vs. max reads
    float tsum = red[rA][0];
#pragma unroll
    for (int k = 1; k < 16; ++k) tsum += red[rA][k];
    const float alpha = __expf(m_old - m_new);
    if (cA == 0) {
      m_sh[rA]     = m_new;
      l_sh[rA]     = l_sh[rA] * alpha + tsum;
      alpha_sh[rA] = alpha;
    }
    __syncthreads();  // p_tile + alpha ready for all waves

    // ---- rescale accumulators, then accumulate P-tile @ h-tile ----
    const float al0 = alpha_sh[w];
    const float al1 = alpha_sh[w + 4];
    const float al2 = alpha_sh[w + 8];
    const float al3 = alpha_sh[w + 12];
    acc0.x *= al0; acc0.y *= al0; acc0.z *= al0; acc0.w *= al0;
    acc1.x *= al1; acc1.y *= al1; acc1.z *= al1; acc1.w *= al1;
    acc2.x *= al2; acc2.y *= al2; acc2.z *= al2; acc2.w *= al2;
    acc3.x *= al3; acc3.y *= al3; acc3.z *= al3; acc3.w *= al3;

    const float* hp = h + (size_t)j0 * DDIM + 4 * cg;
#pragma unroll 4
    for (int jj = 0; jj < BN; ++jj) {
      const float4 hv = *(const float4*)(hp + (size_t)jj * DDIM);
      const float p0 = p_tile[w][jj];       // wave-uniform LDS broadcasts
      const float p1 = p_tile[w + 4][jj];
      const float p2 = p_tile[w + 8][jj];
      const float p3 = p_tile[w + 12][jj];
      acc0.x += p0 * hv.x; acc0.y += p0 * hv.y; acc0.z += p0 * hv.z; acc0.w += p0 * hv.w;
      acc1.x += p1 * hv.x; acc1.y += p1 * hv.y; acc1.z += p1 * hv.z; acc1.w += p1 * hv.w;
      acc2.x += p2 * hv.x; acc2.y += p2 * hv.y; acc2.z += p2 * hv.z; acc2.w += p2 * hv.w;
      acc3.x += p3 * hv.x; acc3.y += p3 * hv.y; acc3.z += p3 * hv.z; acc3.w += p3 * hv.w;
    }
    __syncthreads();  // protect p_tile/s2t before next tile overwrite
  }

  // ---- finalize: divide by row sums (l >= 1 always: max element contributes 1)
  const float r0i = 1.f / l_sh[w];
  const float r1i = 1.f / l_sh[w + 4];
  const float r2i = 1.f / l_sh[w + 8];
  const float r3i = 1.f / l_sh[w + 12];
  float4 o;
  o = make_float4(acc0.x * r0i, acc0.y * r0i, acc0.z * r0i, acc0.w * r0i);
  *(float4*)(out + (size_t)(r0 + w) * DDIM + 4 * cg) = o;
  o = make_float4(acc1.x * r1i, acc1.y * r1i, acc1.z * r1i, acc1.w * r1i);
  *(float4*)(out + (size_t)(r0 + w + 4) * DDIM + 4 * cg) = o;
  o = make_float4(acc2.x * r2i, acc2.y * r2i, acc2.z * r2i, acc2.w * r2i);
  *(float4*)(out + (size_t)(r0 + w + 8) * DDIM + 4 * cg) = o;
  o = make_float4(acc3.x * r3i, acc3.y * r3i, acc3.z * r3i, acc3.w * r3i);
  *(float4*)(out + (size_t)(r0 + w + 12) * DDIM + 4 * cg) = o;
}

extern "C" void kernel_launch(void* const* d_in, const int* in_sizes, int n_in,
                              void* d_out, int out_size, void* d_ws, size_t ws_size,
                              hipStream_t stream) {
  const float* h   = (const float*)d_in[0];
  const int*   adj = (const int*)d_in[1];
  const float* a   = (const float*)d_in[2];
  float* out = (float*)d_out;
  float* s1  = (float*)d_ws;            // NTOT floats
  float* s2  = s1 + NTOT;               // NTOT floats (64 KB total in ws)

  gat_scores<<<NTOT / 4, 256, 0, stream>>>(h, a, s1, s2);
  gat_attn<<<NTOT / BM, 256, 0, stream>>>(h, adj, s1, s2, out);
}

// Round 2
// 687.428 us; speedup vs baseline: 1.5199x; 1.5199x over previous
//
#include <hip/hip_runtime.h>
#include <hip/hip_bf16.h>

#define NTOT 8192
#define DDIM 256
#define BM 16
#define BN 256
#define PSTR (BN + 8)        // bf16 elems per p_lds row (+8 => 2-way LDS alias only)
#define NEG_BIG -9e15f

typedef __attribute__((ext_vector_type(8))) short short8;
typedef __attribute__((ext_vector_type(4))) float floatx4;

// ---------------- Kernel 1: per-row scores s1 = h@a[:D], s2 = h@a[D:] -------
__global__ __launch_bounds__(256) void gat_scores(const float* __restrict__ h,
                                                  const float* __restrict__ a,
                                                  float* __restrict__ s1,
                                                  float* __restrict__ s2) {
  int row  = blockIdx.x * 4 + (threadIdx.x >> 6);
  int lane = threadIdx.x & 63;
  const float* hr = h + (size_t)row * DDIM;
  float p1 = 0.f, p2 = 0.f;
#pragma unroll
  for (int k = 0; k < DDIM / 64; ++k) {
    int idx  = lane + 64 * k;
    float hv = hr[idx];
    p1 += hv * a[idx];
    p2 += hv * a[DDIM + idx];
  }
#pragma unroll
  for (int off = 32; off > 0; off >>= 1) {
    p1 += __shfl_down(p1, off, 64);
    p2 += __shfl_down(p2, off, 64);
  }
  if (lane == 0) { s1[row] = p1; s2[row] = p2; }
}

// ---------------- Kernel 2: hT[d][i] = bf16(h[i][d]) ------------------------
__global__ __launch_bounds__(256) void gat_transpose(const float* __restrict__ h,
                                                     ushort* __restrict__ hT) {
  __shared__ float tile[64][65];
  const int i0 = blockIdx.x * 64, d0 = blockIdx.y * 64;
  const int t = threadIdx.x;
  const int c = t & 63, r4 = t >> 6;
#pragma unroll
  for (int it = 0; it < 16; ++it) {
    int r = r4 + 4 * it;
    tile[r][c] = h[(size_t)(i0 + r) * DDIM + d0 + c];   // coalesced read
  }
  __syncthreads();
#pragma unroll
  for (int it = 0; it < 16; ++it) {
    int d = r4 + 4 * it;
    float v = tile[c][d];                                // stride-65: conflict-free
    __hip_bfloat16 b = __float2bfloat16(v);
    hT[(size_t)(d0 + d) * NTOT + i0 + c] = *(ushort*)&b; // coalesced 2B x64 write
  }
}

// ---------------- Kernel 3: fused masked softmax + P@h via MFMA -------------
// 512 blocks x 256 thr. Block owns BM=16 out rows. Wave w: softmax rows 4w..4w+3,
// MFMA d-slice [64w, 64w+64). A-frags from LDS p tile, B-frags from global hT (L2).
__global__ __launch_bounds__(256) void gat_attn(const ushort* __restrict__ hT,
                                                const int*   __restrict__ adj,
                                                const float* __restrict__ s1g,
                                                const float* __restrict__ s2g,
                                                float* __restrict__ out) {
  __shared__ ushort p_lds[BM * PSTR];
  __shared__ float  alpha_lds[BM];
  __shared__ float  l_lds[BM];

  const int t    = threadIdx.x;
  const int lane = t & 63;
  const int w    = t >> 6;
  const int quad = lane >> 4;
  const int col  = lane & 15;
  const int r0   = blockIdx.x * BM;
  const int d0   = w * 64;

  float m_prev[4], l_run[4];
#pragma unroll
  for (int rr = 0; rr < 4; ++rr) { m_prev[rr] = NEG_BIG; l_run[rr] = 0.f; }

  floatx4 acc[4];
#pragma unroll
  for (int nt = 0; nt < 4; ++nt) acc[nt] = (floatx4){0.f, 0.f, 0.f, 0.f};

  float s1v[4];
#pragma unroll
  for (int rr = 0; rr < 4; ++rr) s1v[rr] = s1g[r0 + 4 * w + rr];

  const int* adj_base = adj + (size_t)(r0 + 4 * w) * NTOT + 4 * lane;
  int4 adjv[4];
#pragma unroll
  for (int rr = 0; rr < 4; ++rr)
    adjv[rr] = *(const int4*)(adj_base + (size_t)rr * NTOT);

  for (int j0 = 0; j0 < NTOT; j0 += BN) {
    // ---- phase 1: logits + online softmax for this wave's 4 rows ----
    float4 s2v = *(const float4*)(s2g + j0 + 4 * lane);
#pragma unroll
    for (int rr = 0; rr < 4; ++rr) {
      float e[4];
      e[0] = s1v[rr] + s2v.x; e[1] = s1v[rr] + s2v.y;
      e[2] = s1v[rr] + s2v.z; e[3] = s1v[rr] + s2v.w;
      const int* am = (const int*)&adjv[rr];
#pragma unroll
      for (int i = 0; i < 4; ++i) {
        float ee = e[i];
        ee   = ee > 0.f ? ee : 0.01f * ee;   // leaky_relu(0.01)
        e[i] = am[i] > 0 ? ee : NEG_BIG;     // mask
      }
      float mx = fmaxf(fmaxf(e[0], e[1]), fmaxf(e[2], e[3]));
#pragma unroll
      for (int off = 1; off < 64; off <<= 1)
        mx = fmaxf(mx, __shfl_xor(mx, off, 64));
      const float m_new = fmaxf(m_prev[rr], mx);
      const float al    = __expf(m_prev[rr] - m_new);
      float ls = 0.f;
      ushort4 pu;
      ushort* pp = (ushort*)&pu;
#pragma unroll
      for (int i = 0; i < 4; ++i) {
        float p = __expf(e[i] - m_new);      // NEG_BIG path underflows to 0
        ls += p;
        __hip_bfloat16 b = __float2bfloat16(p);
        pp[i] = *(ushort*)&b;
      }
#pragma unroll
      for (int off = 1; off < 64; off <<= 1)
        ls += __shfl_xor(ls, off, 64);
      l_run[rr]  = l_run[rr] * al + ls;
      m_prev[rr] = m_new;
      *(ushort4*)&p_lds[(4 * w + rr) * PSTR + 4 * lane] = pu;
      if (lane == 0) alpha_lds[4 * w + rr] = al;
    }

    // ---- prefetch next adj tile (latency hides under MFMA phase) ----
    if (j0 + BN < NTOT) {
#pragma unroll
      for (int rr = 0; rr < 4; ++rr)
        adjv[rr] = *(const int4*)(adj_base + (size_t)rr * NTOT + (j0 + BN));
    }
    __syncthreads();

    // ---- phase 2: rescale acc, then MFMA accumulate P-tile @ h-tile ----
    float4 al4 = *(const float4*)&alpha_lds[quad * 4];   // same-addr broadcast
    float alr[4] = {al4.x, al4.y, al4.z, al4.w};
#pragma unroll
    for (int nt = 0; nt < 4; ++nt) {
      acc[nt][0] *= alr[0]; acc[nt][1] *= alr[1];
      acc[nt][2] *= alr[2]; acc[nt][3] *= alr[3];
    }

    const ushort* hTb = hT + (size_t)(d0 + col) * NTOT + j0 + quad * 8;
    const ushort* pA  = &p_lds[col * PSTR + quad * 8];
#pragma unroll
    for (int kt = 0; kt < 8; ++kt) {
      short8 afr = *(const short8*)(pA + 32 * kt);       // ds_read_b128, 2-way ok
#pragma unroll
      for (int nt = 0; nt < 4; ++nt) {
        short8 bfr = *(const short8*)(hTb + (size_t)(16 * nt) * NTOT + 32 * kt);
        acc[nt] = __builtin_amdgcn_mfma_f32_16x16x32_bf16(afr, bfr, acc[nt], 0, 0, 0);
      }
    }
    __syncthreads();   // protect p_lds/alpha_lds before next tile
  }

  // ---- epilogue: divide by row sums, store ----
  if (lane == 0) {
#pragma unroll
    for (int rr = 0; rr < 4; ++rr) l_lds[4 * w + rr] = l_run[rr];
  }
  __syncthreads();
  float4 li4 = *(const float4*)&l_lds[quad * 4];
  float li[4] = {1.f / li4.x, 1.f / li4.y, 1.f / li4.z, 1.f / li4.w};
  float* ob = out + (size_t)(r0 + quad * 4) * DDIM + d0 + col;
#pragma unroll
  for (int nt = 0; nt < 4; ++nt) {
#pragma unroll
    for (int reg = 0; reg < 4; ++reg) {
      ob[(size_t)reg * DDIM + 16 * nt] = acc[nt][reg] * li[reg];
    }
  }
}

extern "C" void kernel_launch(void* const* d_in, const int* in_sizes, int n_in,
                              void* d_out, int out_size, void* d_ws, size_t ws_size,
                              hipStream_t stream) {
  const float* h   = (const float*)d_in[0];
  const int*   adj = (const int*)d_in[1];
  const float* a   = (const float*)d_in[2];
  float* out = (float*)d_out;
  float*  s1 = (float*)d_ws;                 // NTOT floats
  float*  s2 = s1 + NTOT;                    // NTOT floats
  ushort* hT = (ushort*)(s2 + NTOT);         // DDIM*NTOT bf16 = 4 MB

  gat_scores<<<NTOT / 4, 256, 0, stream>>>(h, a, s1, s2);
  gat_transpose<<<dim3(NTOT / 64, DDIM / 64), 256, 0, stream>>>(h, hT);
  gat_attn<<<NTOT / BM, 256, 0, stream>>>(hT, adj, s1, s2, out);
}

// Round 3
// 531.430 us; speedup vs baseline: 1.9661x; 1.2935x over previous
//
#include <hip/hip_runtime.h>
#include <hip/hip_bf16.h>

#define NTOT 8192
#define DDIM 256
#define BM 32
#define BN 256
#define SPLIT 4
#define JCHUNK (NTOT / SPLIT)     // 2048
#define NTILES (JCHUNK / BN)      // 8
#define PSTR (BN + 8)             // bf16 elems per p row: pad 8 -> mild conflicts only
#define NEG_BIG -9e15f

typedef __attribute__((ext_vector_type(8))) short short8;
typedef __attribute__((ext_vector_type(4))) float floatx4;

// ---------------- zero out + lsum (out is poisoned 0xAA each launch) --------
__global__ __launch_bounds__(256) void gat_zero(float* __restrict__ out,
                                                float* __restrict__ lsum) {
  int b = blockIdx.x;
  out[(size_t)b * DDIM + threadIdx.x] = 0.f;
  if (b < NTOT / 256) lsum[b * 256 + threadIdx.x] = 0.f;
}

// ---------------- per-row scores s1 = h@a[:D], s2 = h@a[D:] -----------------
__global__ __launch_bounds__(256) void gat_scores(const float* __restrict__ h,
                                                  const float* __restrict__ a,
                                                  float* __restrict__ s1,
                                                  float* __restrict__ s2) {
  int row  = blockIdx.x * 4 + (threadIdx.x >> 6);
  int lane = threadIdx.x & 63;
  const float* hr = h + (size_t)row * DDIM;
  float p1 = 0.f, p2 = 0.f;
#pragma unroll
  for (int k = 0; k < DDIM / 64; ++k) {
    int idx  = lane + 64 * k;
    float hv = hr[idx];
    p1 += hv * a[idx];
    p2 += hv * a[DDIM + idx];
  }
#pragma unroll
  for (int off = 32; off > 0; off >>= 1) {
    p1 += __shfl_down(p1, off, 64);
    p2 += __shfl_down(p2, off, 64);
  }
  if (lane == 0) { s1[row] = p1; s2[row] = p2; }
}

// ---------------- global max of s2 (for the fixed per-row softmax bound) ----
__global__ __launch_bounds__(256) void gat_s2max(const float* __restrict__ s2,
                                                 float* __restrict__ m2) {
  __shared__ float red[256];
  int t = threadIdx.x;
  float v = -3.4e38f;
  for (int i = t; i < NTOT; i += 256) v = fmaxf(v, s2[i]);
  red[t] = v;
  __syncthreads();
  for (int s = 128; s > 0; s >>= 1) {
    if (t < s) red[t] = fmaxf(red[t], red[t + s]);
    __syncthreads();
  }
  if (t == 0) m2[0] = red[0];
}

// ---------------- hT[d][i] = bf16(h[i][d]) ----------------------------------
__global__ __launch_bounds__(256) void gat_transpose(const float* __restrict__ h,
                                                     ushort* __restrict__ hT) {
  __shared__ float tile[64][65];
  const int i0 = blockIdx.x * 64, d0 = blockIdx.y * 64;
  const int t = threadIdx.x;
  const int c = t & 63, r4 = t >> 6;
#pragma unroll
  for (int it = 0; it < 16; ++it) {
    int r = r4 + 4 * it;
    tile[r][c] = h[(size_t)(i0 + r) * DDIM + d0 + c];
  }
  __syncthreads();
#pragma unroll
  for (int it = 0; it < 16; ++it) {
    int d = r4 + 4 * it;
    float v = tile[c][d];
    __hip_bfloat16 b = __float2bfloat16(v);
    hT[(size_t)(d0 + d) * NTOT + i0 + c] = *(ushort*)&b;
  }
}

// ---------------- fused masked softmax (fixed max) + P@h via MFMA -----------
// Grid (NTOT/BM, SPLIT) x 512 thr. Block: rows [r0,r0+32), j in [jbase,jbase+2048).
// Fixed m_i = lrelu(s1_i + max s2) => partials combine by addition (atomicAdd).
// Wave w: d-slice [32w, 32w+32) (nt=2), all 32 rows (rst=2) -> 32 MFMA/tile.
__global__ __launch_bounds__(512, 4) void gat_attn(const ushort* __restrict__ hT,
                                                   const int*   __restrict__ adj,
                                                   const float* __restrict__ s1g,
                                                   const float* __restrict__ s2g,
                                                   const float* __restrict__ m2g,
                                                   float* __restrict__ lsum,
                                                   float* __restrict__ out) {
  __shared__ ushort pbuf[2][BM * PSTR];

  const int t    = threadIdx.x;
  const int lane = t & 63;
  const int w    = t >> 6;
  const int quad = lane >> 4;
  const int col  = lane & 15;
  const int r0    = blockIdx.x * BM;
  const int jbase = blockIdx.y * JCHUNK;
  const int d0    = w * 32;
  // phase-1 roles: thread -> row (t>>4), 16 contiguous j starting at (t&15)*16
  const int prow = t >> 4;
  const int jc   = (t & 15) * 16;

  const float s1v = s1g[r0 + prow];
  float me = s1v + m2g[0];
  me = me > 0.f ? me : 0.01f * me;          // upper bound on row logits (lrelu monotone)

  const int* adjp = adj + (size_t)(r0 + prow) * NTOT + jbase + jc;
  int4 a4[4];
#pragma unroll
  for (int g = 0; g < 4; ++g) a4[g] = ((const int4*)adjp)[g];

  float lpart = 0.f;
  floatx4 acc[2][2];
#pragma unroll
  for (int r = 0; r < 2; ++r)
#pragma unroll
    for (int n = 0; n < 2; ++n) acc[r][n] = (floatx4){0.f, 0.f, 0.f, 0.f};

  for (int jt = 0; jt < NTILES; ++jt) {
    const int j0 = jbase + jt * BN;

    // ---- phase 1: p = adj ? exp(lrelu(s1+s2) - m) : 0, bf16 -> LDS ----
    short8 p0, p1;
    const float* s2p = s2g + j0 + jc;
#pragma unroll
    for (int g = 0; g < 4; ++g) {
      float4 s2v = ((const float4*)s2p)[g];
      const int* am = (const int*)&a4[g];
      float ev[4] = {s2v.x, s2v.y, s2v.z, s2v.w};
#pragma unroll
      for (int i = 0; i < 4; ++i) {
        float e = s1v + ev[i];
        e = e > 0.f ? e : 0.01f * e;         // leaky_relu(0.01)
        float p = am[i] > 0 ? __expf(e - me) : 0.f;
        lpart += p;
        __hip_bfloat16 b = __float2bfloat16(p);
        if (g < 2) p0[4 * g + i] = *(short*)&b;
        else       p1[4 * (g - 2) + i] = *(short*)&b;
      }
    }
    ushort* pd = &pbuf[jt & 1][prow * PSTR + jc];
    *(short8*)pd       = p0;                 // ds_write_b128 x2
    *(short8*)(pd + 8) = p1;

    // ---- prefetch next adj tile into registers (hides under MFMA phase) ----
    if (jt + 1 < NTILES) {
      const int4* ap = (const int4*)(adjp + (jt + 1) * BN);
#pragma unroll
      for (int g = 0; g < 4; ++g) a4[g] = ap[g];
    }
    __syncthreads();   // single barrier/tile; double-buffer covers WAR hazard

    // ---- phase 2: 2x2 register-blocked MFMA, B-frags from L2-resident hT ----
    const ushort* pb = pbuf[jt & 1];
    const ushort* hb = hT + (size_t)(d0 + col) * NTOT + j0 + quad * 8;
#pragma unroll
    for (int kt = 0; kt < 8; ++kt) {
      short8 af0 = *(const short8*)&pb[col * PSTR + kt * 32 + quad * 8];
      short8 af1 = *(const short8*)&pb[(16 + col) * PSTR + kt * 32 + quad * 8];
      short8 bf0 = *(const short8*)(hb + kt * 32);
      short8 bf1 = *(const short8*)(hb + (size_t)16 * NTOT + kt * 32);
      acc[0][0] = __builtin_amdgcn_mfma_f32_16x16x32_bf16(af0, bf0, acc[0][0], 0, 0, 0);
      acc[1][0] = __builtin_amdgcn_mfma_f32_16x16x32_bf16(af1, bf0, acc[1][0], 0, 0, 0);
      acc[0][1] = __builtin_amdgcn_mfma_f32_16x16x32_bf16(af0, bf1, acc[0][1], 0, 0, 0);
      acc[1][1] = __builtin_amdgcn_mfma_f32_16x16x32_bf16(af1, bf1, acc[1][1], 0, 0, 0);
    }
  }

  // ---- combine partials: l via 16-lane butterfly + atomic, acc via atomics ----
#pragma unroll
  for (int off = 1; off < 16; off <<= 1) lpart += __shfl_xor(lpart, off, 64);
  if ((t & 15) == 0) atomicAdd(&lsum[r0 + prow], lpart);

#pragma unroll
  for (int r = 0; r < 2; ++r)
#pragma unroll
    for (int n = 0; n < 2; ++n)
#pragma unroll
      for (int reg = 0; reg < 4; ++reg)
        atomicAdd(&out[(size_t)(r0 + r * 16 + quad * 4 + reg) * DDIM + d0 + n * 16 + col],
                  acc[r][n][reg]);
}

// ---------------- finalize: out[i][d] /= l[i] -------------------------------
__global__ __launch_bounds__(256) void gat_finalize(float* __restrict__ out,
                                                    const float* __restrict__ lsum) {
  int r = blockIdx.x;
  float inv = 1.0f / lsum[r];
  out[(size_t)r * DDIM + threadIdx.x] *= inv;
}

extern "C" void kernel_launch(void* const* d_in, const int* in_sizes, int n_in,
                              void* d_out, int out_size, void* d_ws, size_t ws_size,
                              hipStream_t stream) {
  const float* h   = (const float*)d_in[0];
  const int*   adj = (const int*)d_in[1];
  const float* a   = (const float*)d_in[2];
  float* out = (float*)d_out;

  float*  s1   = (float*)d_ws;               // NTOT
  float*  s2   = s1 + NTOT;                  // NTOT
  float*  m2   = s2 + NTOT;                  // 64 (padded)
  float*  lsum = m2 + 64;                    // NTOT
  ushort* hT   = (ushort*)(lsum + NTOT);     // DDIM*NTOT bf16 = 4 MB (16B-aligned)

  gat_zero<<<NTOT, 256, 0, stream>>>(out, lsum);
  gat_scores<<<NTOT / 4, 256, 0, stream>>>(h, a, s1, s2);
  gat_s2max<<<1, 256, 0, stream>>>(s2, m2);
  gat_transpose<<<dim3(NTOT / 64, DDIM / 64), 256, 0, stream>>>(h, hT);
  gat_attn<<<dim3(NTOT / BM, SPLIT), 512, 0, stream>>>(hT, adj, s1, s2, m2, lsum, out);
  gat_finalize<<<NTOT, 256, 0, stream>>>(out, lsum);
}